// Round 11
// baseline (1886.426 us; speedup 1.0000x reference)
//
#include <hip/hip_runtime.h>
#include <hip/hip_bf16.h>

// Bidirectional GRU encoder, MI355X gfx950.
// Phase 1: prep + one big MFMA GEMM xW = A @ Wcat.
// Phase 2: ONE persistent kernel, grid 128 x 512 (proven co-resident).
//   4 worlds = (dir x batch-half), each 16 rows x 1024 cols on 32 blocks.
//   h exchange is TAGGED DATA: u32 = (bf16<<16)|step_tag, published with one
//   fire-and-forget sc0sc1 store (no drain, no flags); consumers spin-load
//   their slice until all tags match (data load IS the poll). 2 barriers/step.

typedef __attribute__((ext_vector_type(8))) short bf16x8;     // 8 x bf16
typedef __attribute__((ext_vector_type(4))) float f32x4;      // MFMA acc
typedef __attribute__((ext_vector_type(4))) unsigned u32x4;
typedef __attribute__((ext_vector_type(2))) unsigned u32x2;

__device__ __forceinline__ f32x4 mfma_bf16(bf16x8 a, bf16x8 b, f32x4 c) {
  return __builtin_amdgcn_mfma_f32_16x16x32_bf16(a, b, c, 0, 0, 0);
}

// ---- asm memory helpers ----
__device__ __forceinline__ bf16x8 ld_b128(const __hip_bfloat16* p) {       // plain
  bf16x8 r; asm volatile("global_load_dwordx4 %0, %1, off" : "=v"(r) : "v"(p)); return r;
}
__device__ __forceinline__ u32x4 ld_v4_dev(const unsigned* p) {            // device-coherent
  u32x4 r; asm volatile("global_load_dwordx4 %0, %1, off sc0 sc1" : "=v"(r) : "v"(p)); return r;
}
__device__ __forceinline__ unsigned ld_u32_pl(const void* p) {
  unsigned r; asm volatile("global_load_dword %0, %1, off" : "=v"(r) : "v"(p)); return r;
}
__device__ __forceinline__ void st_v2_dev(unsigned* p, u32x2 v) {
  asm volatile("global_store_dwordx2 %0, %1, off sc0 sc1" :: "v"(p), "v"(v) : "memory");
}

__device__ __forceinline__ float bfsel(unsigned wd, int hi) {
  return __uint_as_float(hi ? (wd & 0xFFFF0000u) : (wd << 16));
}
__device__ __forceinline__ unsigned bfbits(float x) {
  return (unsigned)__builtin_bit_cast(unsigned short, __float2bfloat16(x));
}

#define WAITV(N) asm volatile("s_waitcnt vmcnt(" #N ")" ::: "memory")
#define SB0() __builtin_amdgcn_sched_barrier(0)

// ---------------- prep kernels ----------------

__global__ __launch_bounds__(256) void transpose_cast(const float* __restrict__ src,
                                                      __hip_bfloat16* __restrict__ dst,
                                                      int R, int C) {
  __shared__ float tile[32][33];
  const int tid = threadIdx.x;
  const int bc = blockIdx.x * 32;
  const int br = blockIdx.y * 32;
#pragma unroll
  for (int i = 0; i < 4; ++i) {
    int idx = tid + i * 256;
    int r = idx >> 5, c = idx & 31;
    tile[r][c] = src[(size_t)(br + r) * C + bc + c];
  }
  __syncthreads();
#pragma unroll
  for (int i = 0; i < 4; ++i) {
    int idx = tid + i * 256;
    int r = idx >> 5, c = idx & 31;
    dst[(size_t)(bc + r) * R + br + c] = __float2bfloat16(tile[c][r]);
  }
}

__global__ __launch_bounds__(256) void gather_embed(const int* __restrict__ x,
                                                    const float* __restrict__ emb,
                                                    __hip_bfloat16* __restrict__ A) {
  int ch = blockIdx.x * 256 + threadIdx.x;
  int row = ch >> 6, seg = ch & 63;
  int b = row & 31, t = row >> 5;
  int idx = x[b * 256 + t];
  const float* s = emb + (size_t)idx * 512 + seg * 8;
  float4 f0 = *(const float4*)(s);
  float4 f1 = *(const float4*)(s + 4);
  __hip_bfloat16 h[8];
  h[0] = __float2bfloat16(f0.x); h[1] = __float2bfloat16(f0.y);
  h[2] = __float2bfloat16(f0.z); h[3] = __float2bfloat16(f0.w);
  h[4] = __float2bfloat16(f1.x); h[5] = __float2bfloat16(f1.y);
  h[6] = __float2bfloat16(f1.z); h[7] = __float2bfloat16(f1.w);
  *(uint4*)(A + (size_t)row * 512 + seg * 8) = *(const uint4*)h;
}

// H: [4 worlds][2 par][16 rows][1024 tagged u32]
// par0 = (h0<<16)|tag0, par1 = tag 0xFFFF (invalid; also kills replay ABA)
__global__ __launch_bounds__(256) void init_h(const float* __restrict__ h0f,
                                              const float* __restrict__ h0b,
                                              unsigned* __restrict__ H) {
  int i = blockIdx.x * 256 + threadIdx.x;    // [0, 131072)
  int w = i >> 15, rem = i & 32767;
  int par = rem >> 14, rem2 = rem & 16383;
  int row = rem2 >> 10, col = rem2 & 1023;
  unsigned v;
  if (par == 0) {
    const float* h0 = (w & 1) ? h0b : h0f;
    v = bfbits(h0[((w >> 1) * 16 + row) * 1024 + col]) << 16;   // tag 0
  } else {
    v = 0xFFFFu;
  }
  H[i] = v;
}

// ---------------- big GEMM: xW[8192][6144] = A[8192][512] @ WT[6144][512]^T ----------------
__global__ __launch_bounds__(256) void gemm_xw(const __hip_bfloat16* __restrict__ A,
                                               const __hip_bfloat16* __restrict__ B,
                                               __hip_bfloat16* __restrict__ C) {
  __shared__ char sm[2 * 128 * 80];
  const int tid = threadIdx.x;
  const int bn = blockIdx.x, bm = blockIdx.y;
  const int l = tid & 63, w = tid >> 6;
  const int wm = w & 1, wn = w >> 1;
  const int lr = l & 15, lk = l >> 4;
  f32x4 acc[4][4] = {};
  for (int k0 = 0; k0 < 512; k0 += 32) {
    __syncthreads();
#pragma unroll
    for (int i = 0; i < 2; ++i) {
      int ch = tid + i * 256;
      int row = ch >> 2, kq = ch & 3;
      uint4 va = *(const uint4*)(A + (size_t)(bm * 128 + row) * 512 + k0 + kq * 8);
      *(uint4*)(sm + row * 80 + kq * 16) = va;
      uint4 vb = *(const uint4*)(B + (size_t)(bn * 128 + row) * 512 + k0 + kq * 8);
      *(uint4*)(sm + 10240 + row * 80 + kq * 16) = vb;
    }
    __syncthreads();
    bf16x8 af[4], bfr[4];
#pragma unroll
    for (int m = 0; m < 4; ++m)
      af[m] = *(const bf16x8*)(sm + (wm * 64 + m * 16 + lr) * 80 + lk * 16);
#pragma unroll
    for (int n = 0; n < 4; ++n)
      bfr[n] = *(const bf16x8*)(sm + 10240 + (wn * 64 + n * 16 + lr) * 80 + lk * 16);
#pragma unroll
    for (int m = 0; m < 4; ++m)
#pragma unroll
      for (int n = 0; n < 4; ++n)
        acc[m][n] = mfma_bf16(af[m], bfr[n], acc[m][n]);
  }
#pragma unroll
  for (int m = 0; m < 4; ++m)
#pragma unroll
    for (int n = 0; n < 4; ++n)
#pragma unroll
      for (int v = 0; v < 4; ++v) {
        int row = bm * 128 + wm * 64 + m * 16 + lk * 4 + v;
        int col = bn * 128 + wn * 64 + n * 16 + lr;
        C[(size_t)row * 6144 + col] = __float2bfloat16(acc[m][n][v]);
      }
}

// ---------------- persistent GRU: tagged-h worlds ----------------
// grid 128: world w = bi&3 (dir=w&1, batch-half mh=w>>1), rank r = bi>>2.
// Block owns cols r*32..+32. 8 waves = K-split 8 (128 K each), ub pinned.
// Step: [xw issue] [spin-load own tagged slice until tags==s] [pack + 24 MFMA]
//       [barrier C] [xacc write] [barrier B]
//       [tid<256: combine + one 8B tagged publish (no drain) + outputs]
__global__ __launch_bounds__(512, 2) void gru_persist(
    const __hip_bfloat16* __restrict__ xW,
    const __hip_bfloat16* __restrict__ UT,
    const float* __restrict__ bias_f,
    const float* __restrict__ bias_b,
    const float* __restrict__ h0_f,
    const float* __restrict__ h0_b,
    unsigned* H,                // [4][2][16][1024] tagged u32
    float* __restrict__ out) {
  const int bi = blockIdx.x;
  const int w = bi & 3;
  const int r = bi >> 2;
  const int dir = w & 1, mh = w >> 1;
  const int tid = threadIdx.x;
  const int l = tid & 63, q = tid >> 6;
  const int lr = l & 15, lk = l >> 4;
  const int c0 = r * 32;

  __shared__ float xacc[8][6][16][20];   // [q][tile][row][col+pad]

  // ---- pin U: 6 tiles (g,ch), K-slice q*128 ----
  bf16x8 ub[6][4];
#pragma unroll
  for (int g = 0; g < 3; ++g)
#pragma unroll
    for (int ch = 0; ch < 2; ++ch) {
      const __hip_bfloat16* Urow =
          UT + (size_t)(dir * 3072 + g * 1024 + c0 + ch * 16 + lr) * 1024 + q * 128 + lk * 8;
#pragma unroll
      for (int kc = 0; kc < 4; ++kc)
        ub[g * 2 + ch][kc] = ld_b128(Urow + kc * 32);
    }
  WAITV(0);
  SB0();

  // ---- combiner-thread invariants (tid<256): 1 row x 2 cols ----
  const int crow = tid & 15;            // batch row within world
  const int cp = tid >> 4;              // col-pair 0..15 (tid<256)
  const int cb = mh * 16 + crow;        // global batch row
  const int cg = c0 + 2 * cp;           // global h col (even)
  float2 bz0, br0, bn0, bz1, br1, bn1, hp;
  if (tid < 256) {
    const float* bias = dir ? bias_b : bias_f;
    bz0 = *(const float2*)&bias[cg];
    br0 = *(const float2*)&bias[1024 + cg];
    bn0 = *(const float2*)&bias[2048 + cg];
    bz1 = *(const float2*)&bias[3072 + cg];
    br1 = *(const float2*)&bias[4096 + cg];
    bn1 = *(const float2*)&bias[5120 + cg];
    const float* h0 = dir ? h0_b : h0_f;
    hp = *(const float2*)&h0[(size_t)cb * 1024 + cg];
  }

  unsigned* Hw = H + w * 32768;

  for (int s = 0; s < 256; ++s) {
    const int par = s & 1;
    const int t = dir ? (255 - s) : s;

    // ---- xW loads (combiner threads; plain, drained by retry's WAITV) ----
    unsigned xwz = 0, xwr = 0, xwn = 0;
    if (q < 4) {
      const __hip_bfloat16* xp = xW + (size_t)(t * 32 + cb) * 6144 + dir * 3072 + cg;
      xwz = ld_u32_pl(xp);
      xwr = ld_u32_pl(xp + 1024);
      xwn = ld_u32_pl(xp + 2048);
    }

    // ---- tagged h spin-load: lane covers rows lr, K-cols q*128+lk*8 (+kc*32) ----
    const unsigned* hrow = Hw + par * 16384 + lr * 1024 + q * 128 + lk * 8;
    const unsigned tg = (unsigned)s;
    u32x4 ta[8];
    for (;;) {
#pragma unroll
      for (int kc = 0; kc < 4; ++kc) {
        ta[2 * kc]     = ld_v4_dev(hrow + kc * 32);
        ta[2 * kc + 1] = ld_v4_dev(hrow + kc * 32 + 4);
      }
      WAITV(0);
      SB0();
      unsigned bad = 0;
#pragma unroll
      for (int i = 0; i < 8; ++i)
        bad |= (ta[i][0] ^ tg) | (ta[i][1] ^ tg) | (ta[i][2] ^ tg) | (ta[i][3] ^ tg);
      if (__all((bad & 0xFFFFu) == 0)) break;
      __builtin_amdgcn_s_sleep(1);
    }

    // ---- pack hi16 -> bf16x8 fragments, 24 MFMA (pure register phase) ----
    f32x4 acc[6] = {};
#pragma unroll
    for (int kc = 0; kc < 4; ++kc) {
      u32x4 pk;
      pk[0] = (ta[2 * kc][0] >> 16)     | (ta[2 * kc][1] & 0xFFFF0000u);
      pk[1] = (ta[2 * kc][2] >> 16)     | (ta[2 * kc][3] & 0xFFFF0000u);
      pk[2] = (ta[2 * kc + 1][0] >> 16) | (ta[2 * kc + 1][1] & 0xFFFF0000u);
      pk[3] = (ta[2 * kc + 1][2] >> 16) | (ta[2 * kc + 1][3] & 0xFFFF0000u);
      bf16x8 hb = __builtin_bit_cast(bf16x8, pk);
      acc[0] = mfma_bf16(hb, ub[0][kc], acc[0]);
      acc[1] = mfma_bf16(hb, ub[1][kc], acc[1]);
      acc[2] = mfma_bf16(hb, ub[2][kc], acc[2]);
      acc[3] = mfma_bf16(hb, ub[3][kc], acc[3]);
      acc[4] = mfma_bf16(hb, ub[4][kc], acc[4]);
      acc[5] = mfma_bf16(hb, ub[5][kc], acc[5]);
    }

    __syncthreads();   // BARRIER C: xacc(s-1) fully consumed

#pragma unroll
    for (int tile = 0; tile < 6; ++tile)
#pragma unroll
      for (int v = 0; v < 4; ++v)
        xacc[q][tile][lk * 4 + v][lr] = acc[tile][v];
    __syncthreads();   // BARRIER B: xacc(s) complete

    if (tid < 256) {
      const int ch = cp >> 3;                 // 16-col tile half
      const int co = (2 * cp) & 15;           // even col offset in tile
      float2 hz = {0.f, 0.f}, hr = {0.f, 0.f}, hn = {0.f, 0.f};
#pragma unroll
      for (int qq = 0; qq < 8; ++qq) {
        float2 a  = *(const float2*)&xacc[qq][ch][crow][co];
        float2 bq = *(const float2*)&xacc[qq][2 + ch][crow][co];
        float2 c  = *(const float2*)&xacc[qq][4 + ch][crow][co];
        hz.x += a.x;  hz.y += a.y;
        hr.x += bq.x; hr.y += bq.y;
        hn.x += c.x;  hn.y += c.y;
      }
      float hnew[2];
#pragma unroll
      for (int j = 0; j < 2; ++j) {
        const float hzj = j ? hz.y : hz.x, hrj = j ? hr.y : hr.x, hnj = j ? hn.y : hn.x;
        const float bz0j = j ? bz0.y : bz0.x, br0j = j ? br0.y : br0.x, bn0j = j ? bn0.y : bn0.x;
        const float bz1j = j ? bz1.y : bz1.x, br1j = j ? br1.y : br1.x, bn1j = j ? bn1.y : bn1.x;
        const float hpj = j ? hp.y : hp.x;
        const float z  = 1.f / (1.f + expf(-(bfsel(xwz, j) + bz0j + hzj + bz1j)));
        const float rr = 1.f / (1.f + expf(-(bfsel(xwr, j) + br0j + hrj + br1j)));
        const float n  = tanhf(bfsel(xwn, j) + bn0j + rr * (hnj + bn1j));
        hnew[j] = z * hpj + (1.f - z) * n;
      }
      hp.x = hnew[0]; hp.y = hnew[1];
      // fire-and-forget tagged publish (2 words, 8B): data IS the flag
      u32x2 pk2;
      pk2[0] = (bfbits(hnew[0]) << 16) | (unsigned)(s + 1);
      pk2[1] = (bfbits(hnew[1]) << 16) | (unsigned)(s + 1);
      st_v2_dev(Hw + (par ^ 1) * 16384 + crow * 1024 + cg, pk2);
      // off-critical-path outputs (plain)
      *(float2*)&out[((size_t)cb * 256 + t) * 2048 + dir * 1024 + cg] = *(float2*)hnew;
      if (s == 255)
        *(float2*)&out[16777216 + dir * 32768 + (size_t)cb * 1024 + cg] = *(float2*)hnew;
    }
  }
}

// ---------------- host ----------------

extern "C" void kernel_launch(void* const* d_in, const int* in_sizes, int n_in,
                              void* d_out, int out_size, void* d_ws, size_t ws_size,
                              hipStream_t stream) {
  const int*   x    = (const int*)d_in[0];
  const float* emb  = (const float*)d_in[1];
  const float* W_f  = (const float*)d_in[2];
  const float* U_f  = (const float*)d_in[3];
  const float* b_f  = (const float*)d_in[4];
  const float* W_b  = (const float*)d_in[5];
  const float* U_b  = (const float*)d_in[6];
  const float* b_b  = (const float*)d_in[7];
  const float* h0_f = (const float*)d_in[8];
  const float* h0_b = (const float*)d_in[9];
  float* out = (float*)d_out;
  char* ws = (char*)d_ws;

  const size_t SZ_A  = (size_t)8192 * 512 * 2;
  const size_t SZ_WT = (size_t)6144 * 512 * 2;
  const size_t SZ_UT = (size_t)6144 * 1024 * 2;
  const size_t SZ_XW = (size_t)8192 * 6144 * 2;

  __hip_bfloat16* A   = (__hip_bfloat16*)(ws);
  __hip_bfloat16* WT  = (__hip_bfloat16*)(ws + SZ_A);
  __hip_bfloat16* UT  = (__hip_bfloat16*)(ws + SZ_A + SZ_WT);
  __hip_bfloat16* XW  = (__hip_bfloat16*)(ws + SZ_A + SZ_WT + SZ_UT);
  unsigned*       H   = (unsigned*)(ws + SZ_A + SZ_WT + SZ_UT + SZ_XW);

  transpose_cast<<<dim3(96, 16), 256, 0, stream>>>(W_f, WT, 512, 3072);
  transpose_cast<<<dim3(96, 16), 256, 0, stream>>>(W_b, WT + (size_t)3072 * 512, 512, 3072);
  transpose_cast<<<dim3(96, 32), 256, 0, stream>>>(U_f, UT, 1024, 3072);
  transpose_cast<<<dim3(96, 32), 256, 0, stream>>>(U_b, UT + (size_t)3072 * 1024, 1024, 3072);
  gather_embed<<<2048, 256, 0, stream>>>(x, emb, A);
  init_h<<<512, 256, 0, stream>>>(h0_f, h0_b, H);

  gemm_xw<<<dim3(48, 64), 256, 0, stream>>>(A, WT, XW);

  void* args[] = {(void*)&XW, (void*)&UT, (void*)&b_f, (void*)&b_b,
                  (void*)&h0_f, (void*)&h0_b, (void*)&H, (void*)&out};
  hipLaunchCooperativeKernel((void*)gru_persist, dim3(128), dim3(512),
                             args, 0, stream);
}

// Round 12
// 1341.289 us; speedup vs baseline: 1.4064x; 1.4064x over previous
//
#include <hip/hip_runtime.h>
#include <hip/hip_bf16.h>

// Bidirectional GRU encoder, MI355X gfx950.
// Phase 1: prep + one big MFMA GEMM xW = A @ Wcat.
// Phase 2: ONE persistent kernel, grid 128 x 512 (proven co-resident).
//   4 worlds = (dir x batch-half), each 16 rows x 1024 cols on 32 blocks.
//   Sync (R12): per-combiner-WAVE flags packed 4-per-16B-line per block,
//   signaled EARLY (right after each wave's own publish drain). Consumer
//   wave q polls its 4 producer blocks' lines with one dwordx4 per lane.
//   No barrier A, no wave0 relay. 2 barriers/step. Device-scope sc0sc1.

typedef __attribute__((ext_vector_type(8))) short bf16x8;     // 8 x bf16
typedef __attribute__((ext_vector_type(4))) float f32x4;      // MFMA acc
typedef __attribute__((ext_vector_type(4))) unsigned u32x4;
typedef __attribute__((ext_vector_type(2))) unsigned u32x2;

__device__ __forceinline__ f32x4 mfma_bf16(bf16x8 a, bf16x8 b, f32x4 c) {
  return __builtin_amdgcn_mfma_f32_16x16x32_bf16(a, b, c, 0, 0, 0);
}

// ---- asm memory helpers ----
__device__ __forceinline__ bf16x8 ld_b128(const __hip_bfloat16* p) {       // plain
  bf16x8 r; asm volatile("global_load_dwordx4 %0, %1, off" : "=v"(r) : "v"(p)); return r;
}
__device__ __forceinline__ bf16x8 ld_b128_dev(const unsigned* p) {         // device-coherent
  bf16x8 r; asm volatile("global_load_dwordx4 %0, %1, off sc0 sc1" : "=v"(r) : "v"(p)); return r;
}
__device__ __forceinline__ u32x4 ld_v4_dev(const unsigned* p) {
  u32x4 r; asm volatile("global_load_dwordx4 %0, %1, off sc0 sc1" : "=v"(r) : "v"(p)); return r;
}
__device__ __forceinline__ unsigned ld_u32_pl(const void* p) {
  unsigned r; asm volatile("global_load_dword %0, %1, off" : "=v"(r) : "v"(p)); return r;
}
__device__ __forceinline__ void st_u32_dev(unsigned* p, unsigned v) {
  asm volatile("global_store_dword %0, %1, off sc0 sc1" :: "v"(p), "v"(v) : "memory");
}
__device__ __forceinline__ void st_v2_dev(unsigned* p, u32x2 v) {
  asm volatile("global_store_dwordx2 %0, %1, off sc0 sc1" :: "v"(p), "v"(v) : "memory");
}

__device__ __forceinline__ float bfsel(unsigned wd, int hi) {
  return __uint_as_float(hi ? (wd & 0xFFFF0000u) : (wd << 16));
}
__device__ __forceinline__ unsigned bfbits(float x) {
  return (unsigned)__builtin_bit_cast(unsigned short, __float2bfloat16(x));
}

#define WAITV(N) asm volatile("s_waitcnt vmcnt(" #N ")" ::: "memory")
#define SB0() __builtin_amdgcn_sched_barrier(0)

// ---------------- prep kernels ----------------

__global__ __launch_bounds__(256) void transpose_cast(const float* __restrict__ src,
                                                      __hip_bfloat16* __restrict__ dst,
                                                      int R, int C) {
  __shared__ float tile[32][33];
  const int tid = threadIdx.x;
  const int bc = blockIdx.x * 32;
  const int br = blockIdx.y * 32;
#pragma unroll
  for (int i = 0; i < 4; ++i) {
    int idx = tid + i * 256;
    int r = idx >> 5, c = idx & 31;
    tile[r][c] = src[(size_t)(br + r) * C + bc + c];
  }
  __syncthreads();
#pragma unroll
  for (int i = 0; i < 4; ++i) {
    int idx = tid + i * 256;
    int r = idx >> 5, c = idx & 31;
    dst[(size_t)(bc + r) * R + br + c] = __float2bfloat16(tile[c][r]);
  }
}

__global__ __launch_bounds__(256) void gather_embed(const int* __restrict__ x,
                                                    const float* __restrict__ emb,
                                                    __hip_bfloat16* __restrict__ A) {
  int ch = blockIdx.x * 256 + threadIdx.x;
  int row = ch >> 6, seg = ch & 63;
  int b = row & 31, t = row >> 5;
  int idx = x[b * 256 + t];
  const float* s = emb + (size_t)idx * 512 + seg * 8;
  float4 f0 = *(const float4*)(s);
  float4 f1 = *(const float4*)(s + 4);
  __hip_bfloat16 h[8];
  h[0] = __float2bfloat16(f0.x); h[1] = __float2bfloat16(f0.y);
  h[2] = __float2bfloat16(f0.z); h[3] = __float2bfloat16(f0.w);
  h[4] = __float2bfloat16(f1.x); h[5] = __float2bfloat16(f1.y);
  h[6] = __float2bfloat16(f1.z); h[7] = __float2bfloat16(f1.w);
  *(uint4*)(A + (size_t)row * 512 + seg * 8) = *(const uint4*)h;
}

// H: [4 worlds][2 par][16 rows][512 u32(bf16-pair)]
// FLG: [4 worlds][32 blocks][4 waves] u32 dense (16B line per block)
__global__ __launch_bounds__(256) void init_h(const float* __restrict__ h0f,
                                              const float* __restrict__ h0b,
                                              unsigned* __restrict__ H,
                                              unsigned* __restrict__ FLG) {
  int i = blockIdx.x * 256 + threadIdx.x;    // [0, 32768)
  int w = i >> 13, rem = i & 8191;
  int row = rem >> 9, p = rem & 511;
  const float* h0 = (w & 1) ? h0b : h0f;
  int b = (w >> 1) * 16 + row;
  float f0 = h0[b * 1024 + 2 * p];
  float f1 = h0[b * 1024 + 2 * p + 1];
  H[w * 16384 + row * 512 + p] = bfbits(f0) | (bfbits(f1) << 16);
  if (i < 512) FLG[i] = 0u;
}

// ---------------- big GEMM: xW[8192][6144] = A[8192][512] @ WT[6144][512]^T ----------------
__global__ __launch_bounds__(256) void gemm_xw(const __hip_bfloat16* __restrict__ A,
                                               const __hip_bfloat16* __restrict__ B,
                                               __hip_bfloat16* __restrict__ C) {
  __shared__ char sm[2 * 128 * 80];
  const int tid = threadIdx.x;
  const int bn = blockIdx.x, bm = blockIdx.y;
  const int l = tid & 63, w = tid >> 6;
  const int wm = w & 1, wn = w >> 1;
  const int lr = l & 15, lk = l >> 4;
  f32x4 acc[4][4] = {};
  for (int k0 = 0; k0 < 512; k0 += 32) {
    __syncthreads();
#pragma unroll
    for (int i = 0; i < 2; ++i) {
      int ch = tid + i * 256;
      int row = ch >> 2, kq = ch & 3;
      uint4 va = *(const uint4*)(A + (size_t)(bm * 128 + row) * 512 + k0 + kq * 8);
      *(uint4*)(sm + row * 80 + kq * 16) = va;
      uint4 vb = *(const uint4*)(B + (size_t)(bn * 128 + row) * 512 + k0 + kq * 8);
      *(uint4*)(sm + 10240 + row * 80 + kq * 16) = vb;
    }
    __syncthreads();
    bf16x8 af[4], bfr[4];
#pragma unroll
    for (int m = 0; m < 4; ++m)
      af[m] = *(const bf16x8*)(sm + (wm * 64 + m * 16 + lr) * 80 + lk * 16);
#pragma unroll
    for (int n = 0; n < 4; ++n)
      bfr[n] = *(const bf16x8*)(sm + 10240 + (wn * 64 + n * 16 + lr) * 80 + lk * 16);
#pragma unroll
    for (int m = 0; m < 4; ++m)
#pragma unroll
      for (int n = 0; n < 4; ++n)
        acc[m][n] = mfma_bf16(af[m], bfr[n], acc[m][n]);
  }
#pragma unroll
  for (int m = 0; m < 4; ++m)
#pragma unroll
    for (int n = 0; n < 4; ++n)
#pragma unroll
      for (int v = 0; v < 4; ++v) {
        int row = bm * 128 + wm * 64 + m * 16 + lk * 4 + v;
        int col = bn * 128 + wn * 64 + n * 16 + lr;
        C[(size_t)row * 6144 + col] = __float2bfloat16(acc[m][n][v]);
      }
}

// ---------------- persistent GRU: worlds + early per-wave flags ----------------
// grid 128: world w = bi&3 (dir=w&1, batch-half mh=w>>1), rank r = bi>>2.
// Block owns cols r*32..+32. 8 waves = K-split 8 (128 K each), ub pinned.
// Flags: FLG[w][block][wave j] (j = combiner wave 0..3, covers 8 cols).
// Consumer wave q needs producer blocks 4q..4q+3 (all 4 waves each):
// poll = one dwordx4 of block 4q+(l&3)'s line; all 4 words >= s.
// Step: [xw issue(q<4)] [poll own 4 lines] [h dev loads + MFMA ladder]
//       [xacc write] [barrier B] [tid<256: combine -> publish -> WAITV ->
//       lane0 flag(s+1) -> out stores] [barrier C'].
__global__ __launch_bounds__(512, 2) void gru_persist(
    const __hip_bfloat16* __restrict__ xW,
    const __hip_bfloat16* __restrict__ UT,
    const float* __restrict__ bias_f,
    const float* __restrict__ bias_b,
    const float* __restrict__ h0_f,
    const float* __restrict__ h0_b,
    unsigned* H,                // [4][2][16][512] u32
    unsigned* FLG,              // [4][32][4] u32 dense
    float* __restrict__ out) {
  const int bi = blockIdx.x;
  const int w = bi & 3;
  const int r = bi >> 2;
  const int dir = w & 1, mh = w >> 1;
  const int tid = threadIdx.x;
  const int l = tid & 63, q = tid >> 6;
  const int lr = l & 15, lk = l >> 4;
  const int c0 = r * 32;

  __shared__ float xacc[8][6][16][20];   // [q][tile][row][col+pad]

  // ---- pin U: 6 tiles (g,ch), K-slice q*128 ----
  bf16x8 ub[6][4];
#pragma unroll
  for (int g = 0; g < 3; ++g)
#pragma unroll
    for (int ch = 0; ch < 2; ++ch) {
      const __hip_bfloat16* Urow =
          UT + (size_t)(dir * 3072 + g * 1024 + c0 + ch * 16 + lr) * 1024 + q * 128 + lk * 8;
#pragma unroll
      for (int kc = 0; kc < 4; ++kc)
        ub[g * 2 + ch][kc] = ld_b128(Urow + kc * 32);
    }
  WAITV(0);
  SB0();

  // ---- combiner-thread invariants (tid<256): 1 row x 2 cols ----
  const int crow = tid & 15;            // batch row within world
  const int cp = tid >> 4;              // col-pair 0..15 (tid<256)
  const int cb = mh * 16 + crow;        // global batch row
  const int cg = c0 + 2 * cp;           // global h col (even)
  float2 bz0, br0, bn0, bz1, br1, bn1, hp;
  if (tid < 256) {
    const float* bias = dir ? bias_b : bias_f;
    bz0 = *(const float2*)&bias[cg];
    br0 = *(const float2*)&bias[1024 + cg];
    bn0 = *(const float2*)&bias[2048 + cg];
    bz1 = *(const float2*)&bias[3072 + cg];
    br1 = *(const float2*)&bias[4096 + cg];
    bn1 = *(const float2*)&bias[5120 + cg];
    const float* h0 = dir ? h0_b : h0_f;
    hp = *(const float2*)&h0[(size_t)cb * 1024 + cg];
  }

  unsigned* Hw  = H + w * 16384;
  unsigned* FLw = FLG + w * 128;                       // 32 blocks x 4 u32
  const unsigned* flp = FLw + (4 * q + (l & 3)) * 4;   // line of producer block 4q+(l&3)
  unsigned* myflag = FLw + r * 4 + q;                  // combiner wave q<4 owns word q

  for (int s = 0; s < 256; ++s) {
    const int par = s & 1;
    const int t = dir ? (255 - s) : s;

    // ---- xW loads (combiner threads; plain, drained by poll's WAITV) ----
    unsigned xwz = 0, xwr = 0, xwn = 0;
    if (q < 4) {
      const __hip_bfloat16* xp = xW + (size_t)(t * 32 + cb) * 6144 + dir * 3072 + cg;
      xwz = ld_u32_pl(xp);
      xwr = ld_u32_pl(xp + 1024);
      xwn = ld_u32_pl(xp + 2048);
    }

    // ---- poll OWN 4 producer lines (one dwordx4/lane), all 4 waves' flags >= s ----
    {
      const unsigned tg = (unsigned)s;
      for (;;) {
        u32x4 f = ld_v4_dev(flp);
        WAITV(0);
        SB0();
        if (__all(f[0] >= tg && f[1] >= tg && f[2] >= tg && f[3] >= tg)) break;
        __builtin_amdgcn_s_sleep(1);
      }
    }

    // ---- h loads (device-coherent) + MFMA ladder ----
    const unsigned* hrow = Hw + par * 8192 + lr * 512 + q * 64 + lk * 4;
    bf16x8 hb[4];
#pragma unroll
    for (int kc = 0; kc < 4; ++kc)
      hb[kc] = ld_b128_dev(hrow + kc * 16);

    f32x4 acc[6] = {};
#define KSTEP(kc, n)                                                     \
    WAITV(n); SB0();                                                     \
    acc[0] = mfma_bf16(hb[kc], ub[0][kc], acc[0]);                       \
    acc[1] = mfma_bf16(hb[kc], ub[1][kc], acc[1]);                       \
    acc[2] = mfma_bf16(hb[kc], ub[2][kc], acc[2]);                       \
    acc[3] = mfma_bf16(hb[kc], ub[3][kc], acc[3]);                       \
    acc[4] = mfma_bf16(hb[kc], ub[4][kc], acc[4]);                       \
    acc[5] = mfma_bf16(hb[kc], ub[5][kc], acc[5]);
    KSTEP(0, 3) KSTEP(1, 2) KSTEP(2, 1) KSTEP(3, 0)
#undef KSTEP

#pragma unroll
    for (int tile = 0; tile < 6; ++tile)
#pragma unroll
      for (int v = 0; v < 4; ++v)
        xacc[q][tile][lk * 4 + v][lr] = acc[tile][v];
    __syncthreads();   // BARRIER B: xacc(s) complete

    if (tid < 256) {
      const int ch = cp >> 3;                 // 16-col tile half
      const int co = (2 * cp) & 15;           // even col offset in tile
      float2 hz = {0.f, 0.f}, hr = {0.f, 0.f}, hn = {0.f, 0.f};
#pragma unroll
      for (int qq = 0; qq < 8; ++qq) {
        float2 a  = *(const float2*)&xacc[qq][ch][crow][co];
        float2 bq = *(const float2*)&xacc[qq][2 + ch][crow][co];
        float2 c  = *(const float2*)&xacc[qq][4 + ch][crow][co];
        hz.x += a.x;  hz.y += a.y;
        hr.x += bq.x; hr.y += bq.y;
        hn.x += c.x;  hn.y += c.y;
      }
      float hnew[2];
#pragma unroll
      for (int j = 0; j < 2; ++j) {
        const float hzj = j ? hz.y : hz.x, hrj = j ? hr.y : hr.x, hnj = j ? hn.y : hn.x;
        const float bz0j = j ? bz0.y : bz0.x, br0j = j ? br0.y : br0.x, bn0j = j ? bn0.y : bn0.x;
        const float bz1j = j ? bz1.y : bz1.x, br1j = j ? br1.y : br1.x, bn1j = j ? bn1.y : bn1.x;
        const float hpj = j ? hp.y : hp.x;
        const float z  = 1.f / (1.f + expf(-(bfsel(xwz, j) + bz0j + hzj + bz1j)));
        const float rr = 1.f / (1.f + expf(-(bfsel(xwr, j) + br0j + hrj + br1j)));
        const float n  = tanhf(bfsel(xwn, j) + bn0j + rr * (hnj + bn1j));
        hnew[j] = z * hpj + (1.f - z) * n;
      }
      hp.x = hnew[0]; hp.y = hnew[1];
      // critical: publish (4B dev store), own-wave drain, EARLY per-wave flag
      unsigned pk = bfbits(hnew[0]) | (bfbits(hnew[1]) << 16);
      st_u32_dev(Hw + (par ^ 1) * 8192 + crow * 512 + c0 / 2 + cp, pk);
      WAITV(0);
      if (l == 0) st_u32_dev(myflag, (unsigned)(s + 1));
      // off-critical-path outputs (plain)
      *(float2*)&out[((size_t)cb * 256 + t) * 2048 + dir * 1024 + cg] = *(float2*)hnew;
      if (s == 255)
        *(float2*)&out[16777216 + dir * 32768 + (size_t)cb * 1024 + cg] = *(float2*)hnew;
    }
    __syncthreads();   // BARRIER C': xacc(s) consumed; safe to write xacc(s+1)
  }
}

// ---------------- host ----------------

extern "C" void kernel_launch(void* const* d_in, const int* in_sizes, int n_in,
                              void* d_out, int out_size, void* d_ws, size_t ws_size,
                              hipStream_t stream) {
  const int*   x    = (const int*)d_in[0];
  const float* emb  = (const float*)d_in[1];
  const float* W_f  = (const float*)d_in[2];
  const float* U_f  = (const float*)d_in[3];
  const float* b_f  = (const float*)d_in[4];
  const float* W_b  = (const float*)d_in[5];
  const float* U_b  = (const float*)d_in[6];
  const float* b_b  = (const float*)d_in[7];
  const float* h0_f = (const float*)d_in[8];
  const float* h0_b = (const float*)d_in[9];
  float* out = (float*)d_out;
  char* ws = (char*)d_ws;

  const size_t SZ_A  = (size_t)8192 * 512 * 2;
  const size_t SZ_WT = (size_t)6144 * 512 * 2;
  const size_t SZ_UT = (size_t)6144 * 1024 * 2;
  const size_t SZ_XW = (size_t)8192 * 6144 * 2;
  const size_t SZ_H  = (size_t)4 * 16384 * 4;

  __hip_bfloat16* A   = (__hip_bfloat16*)(ws);
  __hip_bfloat16* WT  = (__hip_bfloat16*)(ws + SZ_A);
  __hip_bfloat16* UT  = (__hip_bfloat16*)(ws + SZ_A + SZ_WT);
  __hip_bfloat16* XW  = (__hip_bfloat16*)(ws + SZ_A + SZ_WT + SZ_UT);
  unsigned*       H   = (unsigned*)(ws + SZ_A + SZ_WT + SZ_UT + SZ_XW);
  unsigned*       FLG = (unsigned*)(ws + SZ_A + SZ_WT + SZ_UT + SZ_XW + SZ_H);

  transpose_cast<<<dim3(96, 16), 256, 0, stream>>>(W_f, WT, 512, 3072);
  transpose_cast<<<dim3(96, 16), 256, 0, stream>>>(W_b, WT + (size_t)3072 * 512, 512, 3072);
  transpose_cast<<<dim3(96, 32), 256, 0, stream>>>(U_f, UT, 1024, 3072);
  transpose_cast<<<dim3(96, 32), 256, 0, stream>>>(U_b, UT + (size_t)3072 * 1024, 1024, 3072);
  gather_embed<<<2048, 256, 0, stream>>>(x, emb, A);
  init_h<<<128, 256, 0, stream>>>(h0_f, h0_b, H, FLG);

  gemm_xw<<<dim3(48, 64), 256, 0, stream>>>(A, WT, XW);

  void* args[] = {(void*)&XW, (void*)&UT, (void*)&b_f, (void*)&b_b,
                  (void*)&h0_f, (void*)&h0_b, (void*)&H, (void*)&FLG, (void*)&out};
  hipLaunchCooperativeKernel((void*)gru_persist, dim3(128), dim3(512),
                             args, 0, stream);
}

// Round 13
// 1037.443 us; speedup vs baseline: 1.8183x; 1.2929x over previous
//
#include <hip/hip_runtime.h>
#include <hip/hip_bf16.h>

// Bidirectional GRU encoder, MI355X gfx950.
// Phase 1: prep + one big MFMA GEMM xW = A @ Wcat.
// Phase 2: ONE persistent kernel, grid 128 x 512 (proven co-resident).
//   4 worlds = (dir x batch-half), each 16 rows x 1024 cols on 32 blocks.
//   R9 topology (wave0 polls 32 per-block flags) + R13 fixes: coalesced
//   combiner mapping (lanes = consecutive cols), early flag via LDS
//   monotonic counter, 2 barriers/step. Device-scope sc0sc1 exchange.

typedef __attribute__((ext_vector_type(8))) short bf16x8;     // 8 x bf16
typedef __attribute__((ext_vector_type(4))) float f32x4;      // MFMA acc

__device__ __forceinline__ f32x4 mfma_bf16(bf16x8 a, bf16x8 b, f32x4 c) {
  return __builtin_amdgcn_mfma_f32_16x16x32_bf16(a, b, c, 0, 0, 0);
}

// ---- asm memory helpers ----
__device__ __forceinline__ bf16x8 ld_b128(const __hip_bfloat16* p) {       // plain
  bf16x8 r; asm volatile("global_load_dwordx4 %0, %1, off" : "=v"(r) : "v"(p)); return r;
}
__device__ __forceinline__ bf16x8 ld_b128_dev(const unsigned* p) {         // device-coherent
  bf16x8 r; asm volatile("global_load_dwordx4 %0, %1, off sc0 sc1" : "=v"(r) : "v"(p)); return r;
}
__device__ __forceinline__ unsigned ld_u32_pl(const void* p) {
  unsigned r; asm volatile("global_load_dword %0, %1, off" : "=v"(r) : "v"(p)); return r;
}
__device__ __forceinline__ unsigned ld_u32_dev(const unsigned* p) {
  unsigned r; asm volatile("global_load_dword %0, %1, off sc0 sc1" : "=v"(r) : "v"(p)); return r;
}
__device__ __forceinline__ void st_u32_dev(unsigned* p, unsigned v) {
  asm volatile("global_store_dword %0, %1, off sc0 sc1" :: "v"(p), "v"(v) : "memory");
}

__device__ __forceinline__ float bfsel(unsigned wd, int hi) {
  return __uint_as_float(hi ? (wd & 0xFFFF0000u) : (wd << 16));
}
__device__ __forceinline__ unsigned bfbits(float x) {
  return (unsigned)__builtin_bit_cast(unsigned short, __float2bfloat16(x));
}

#define WAITV(N) asm volatile("s_waitcnt vmcnt(" #N ")" ::: "memory")
#define SB0() __builtin_amdgcn_sched_barrier(0)

// ---------------- prep kernels ----------------

__global__ __launch_bounds__(256) void transpose_cast(const float* __restrict__ src,
                                                      __hip_bfloat16* __restrict__ dst,
                                                      int R, int C) {
  __shared__ float tile[32][33];
  const int tid = threadIdx.x;
  const int bc = blockIdx.x * 32;
  const int br = blockIdx.y * 32;
#pragma unroll
  for (int i = 0; i < 4; ++i) {
    int idx = tid + i * 256;
    int r = idx >> 5, c = idx & 31;
    tile[r][c] = src[(size_t)(br + r) * C + bc + c];
  }
  __syncthreads();
#pragma unroll
  for (int i = 0; i < 4; ++i) {
    int idx = tid + i * 256;
    int r = idx >> 5, c = idx & 31;
    dst[(size_t)(bc + r) * R + br + c] = __float2bfloat16(tile[c][r]);
  }
}

__global__ __launch_bounds__(256) void gather_embed(const int* __restrict__ x,
                                                    const float* __restrict__ emb,
                                                    __hip_bfloat16* __restrict__ A) {
  int ch = blockIdx.x * 256 + threadIdx.x;
  int row = ch >> 6, seg = ch & 63;
  int b = row & 31, t = row >> 5;
  int idx = x[b * 256 + t];
  const float* s = emb + (size_t)idx * 512 + seg * 8;
  float4 f0 = *(const float4*)(s);
  float4 f1 = *(const float4*)(s + 4);
  __hip_bfloat16 h[8];
  h[0] = __float2bfloat16(f0.x); h[1] = __float2bfloat16(f0.y);
  h[2] = __float2bfloat16(f0.z); h[3] = __float2bfloat16(f0.w);
  h[4] = __float2bfloat16(f1.x); h[5] = __float2bfloat16(f1.y);
  h[6] = __float2bfloat16(f1.z); h[7] = __float2bfloat16(f1.w);
  *(uint4*)(A + (size_t)row * 512 + seg * 8) = *(const uint4*)h;
}

// H: [4 worlds][2 par][16 rows][512 u32(bf16-pair)]; FLG: [4][32]*16 stride
__global__ __launch_bounds__(256) void init_h(const float* __restrict__ h0f,
                                              const float* __restrict__ h0b,
                                              unsigned* __restrict__ H,
                                              unsigned* __restrict__ FLG) {
  int i = blockIdx.x * 256 + threadIdx.x;    // [0, 32768)
  int w = i >> 13, rem = i & 8191;
  int row = rem >> 9, p = rem & 511;
  const float* h0 = (w & 1) ? h0b : h0f;
  int b = (w >> 1) * 16 + row;
  float f0 = h0[b * 1024 + 2 * p];
  float f1 = h0[b * 1024 + 2 * p + 1];
  H[w * 16384 + row * 512 + p] = bfbits(f0) | (bfbits(f1) << 16);
  if (i < 2048) FLG[i] = 0u;
}

// ---------------- big GEMM: xW[8192][6144] = A[8192][512] @ WT[6144][512]^T ----------------
__global__ __launch_bounds__(256) void gemm_xw(const __hip_bfloat16* __restrict__ A,
                                               const __hip_bfloat16* __restrict__ B,
                                               __hip_bfloat16* __restrict__ C) {
  __shared__ char sm[2 * 128 * 80];
  const int tid = threadIdx.x;
  const int bn = blockIdx.x, bm = blockIdx.y;
  const int l = tid & 63, w = tid >> 6;
  const int wm = w & 1, wn = w >> 1;
  const int lr = l & 15, lk = l >> 4;
  f32x4 acc[4][4] = {};
  for (int k0 = 0; k0 < 512; k0 += 32) {
    __syncthreads();
#pragma unroll
    for (int i = 0; i < 2; ++i) {
      int ch = tid + i * 256;
      int row = ch >> 2, kq = ch & 3;
      uint4 va = *(const uint4*)(A + (size_t)(bm * 128 + row) * 512 + k0 + kq * 8);
      *(uint4*)(sm + row * 80 + kq * 16) = va;
      uint4 vb = *(const uint4*)(B + (size_t)(bn * 128 + row) * 512 + k0 + kq * 8);
      *(uint4*)(sm + 10240 + row * 80 + kq * 16) = vb;
    }
    __syncthreads();
    bf16x8 af[4], bfr[4];
#pragma unroll
    for (int m = 0; m < 4; ++m)
      af[m] = *(const bf16x8*)(sm + (wm * 64 + m * 16 + lr) * 80 + lk * 16);
#pragma unroll
    for (int n = 0; n < 4; ++n)
      bfr[n] = *(const bf16x8*)(sm + 10240 + (wn * 64 + n * 16 + lr) * 80 + lk * 16);
#pragma unroll
    for (int m = 0; m < 4; ++m)
#pragma unroll
      for (int n = 0; n < 4; ++n)
        acc[m][n] = mfma_bf16(af[m], bfr[n], acc[m][n]);
  }
#pragma unroll
  for (int m = 0; m < 4; ++m)
#pragma unroll
    for (int n = 0; n < 4; ++n)
#pragma unroll
      for (int v = 0; v < 4; ++v) {
        int row = bm * 128 + wm * 64 + m * 16 + lk * 4 + v;
        int col = bn * 128 + wn * 64 + n * 16 + lr;
        C[(size_t)row * 6144 + col] = __float2bfloat16(acc[m][n][v]);
      }
}

// ---------------- persistent GRU: 4 worlds x 32 blocks (R9 + R13 fixes) ----------------
// grid 128: world w = bi&3 (dir=w&1, batch-half mh=w>>1), rank r = bi>>2.
// Block owns cols r*32..+32. 8 waves = K-split 8 (128 K each), ub pinned.
// Step: [xw issue(q<4)] [wave0 poll 32 flags>=s] [WAITV(0)] [barrier A]
//       [hb dev loads + MFMA ladder] [xacc] [barrier B]
//       [tid<256: combine -> coalesced publish -> WAITV(0) -> LDS cnt++;
//        4th wave signals flag(s+1) -> out stores]  (no barrier C)
__global__ __launch_bounds__(512, 2) void gru_persist(
    const __hip_bfloat16* __restrict__ xW,
    const __hip_bfloat16* __restrict__ UT,
    const float* __restrict__ bias_f,
    const float* __restrict__ bias_b,
    const float* __restrict__ h0_f,
    const float* __restrict__ h0_b,
    unsigned* H,                // [4][2][16][512] u32
    unsigned* FLG,              // [4][32] stride-16 u32
    float* __restrict__ out) {
  const int bi = blockIdx.x;
  const int w = bi & 3;
  const int r = bi >> 2;
  const int dir = w & 1, mh = w >> 1;
  const int tid = threadIdx.x;
  const int l = tid & 63, q = tid >> 6;
  const int lr = l & 15, lk = l >> 4;
  const int c0 = r * 32;

  __shared__ float xacc[8][6][16][20];   // [q][tile][row][col+pad]
  __shared__ unsigned cnt;               // monotonic: 4 increments per step

  if (tid == 0) cnt = 0u;

  // ---- pin U: 6 tiles (g,ch), K-slice q*128 ----
  bf16x8 ub[6][4];
#pragma unroll
  for (int g = 0; g < 3; ++g)
#pragma unroll
    for (int ch = 0; ch < 2; ++ch) {
      const __hip_bfloat16* Urow =
          UT + (size_t)(dir * 3072 + g * 1024 + c0 + ch * 16 + lr) * 1024 + q * 128 + lk * 8;
#pragma unroll
      for (int kc = 0; kc < 4; ++kc)
        ub[g * 2 + ch][kc] = ld_b128(Urow + kc * 32);
    }
  WAITV(0);
  SB0();

  // ---- combiner-thread invariants (tid<256): COALESCED mapping ----
  // crow = tid>>4 (row), cp = tid&15 (col-pair): lanes 0..15 -> consecutive cols.
  const int crow = (tid >> 4) & 15;     // batch row within world
  const int cp = tid & 15;              // local col-pair 0..15
  const int cb = mh * 16 + crow;        // global batch row
  const int cg = c0 + 2 * cp;           // global h col (even)
  float2 bz0, br0, bn0, bz1, br1, bn1, hp;
  if (tid < 256) {
    const float* bias = dir ? bias_b : bias_f;
    bz0 = *(const float2*)&bias[cg];
    br0 = *(const float2*)&bias[1024 + cg];
    bn0 = *(const float2*)&bias[2048 + cg];
    bz1 = *(const float2*)&bias[3072 + cg];
    br1 = *(const float2*)&bias[4096 + cg];
    bn1 = *(const float2*)&bias[5120 + cg];
    const float* h0 = dir ? h0_b : h0_f;
    hp = *(const float2*)&h0[(size_t)cb * 1024 + cg];
  }

  unsigned* Hw  = H + w * 16384;
  unsigned* FLw = FLG + w * 512;
  const unsigned* flp = FLw + (l & 31) * 16;   // wave0's poll targets

  for (int s = 0; s < 256; ++s) {
    const int par = s & 1;
    const int t = dir ? (255 - s) : s;

    // ---- xW loads (combiner threads; coalesced 128B runs per 16 lanes) ----
    unsigned xwz = 0, xwr = 0, xwn = 0;
    if (q < 4) {
      const __hip_bfloat16* xp = xW + (size_t)(t * 32 + cb) * 6144 + dir * 3072 + cg;
      xwz = ld_u32_pl(xp);
      xwr = ld_u32_pl(xp + 1024);
      xwn = ld_u32_pl(xp + 2048);
    }

    // ---- wave0 polls world's 32 flags >= s ----
    if (q == 0) {
      const unsigned tg = (unsigned)s;
      for (;;) {
        unsigned f = ld_u32_dev(flp);
        WAITV(0);
        SB0();
        if (__all(f >= tg)) break;
      }
    }
    WAITV(0);          // everyone: 0 outstanding before ladder
    __syncthreads();   // BARRIER A: h(s) readable

    // ---- h loads (device-coherent) + MFMA ladder ----
    const unsigned* hrow = Hw + par * 8192 + lr * 512 + q * 64 + lk * 4;
    bf16x8 hb[4];
#pragma unroll
    for (int kc = 0; kc < 4; ++kc)
      hb[kc] = ld_b128_dev(hrow + kc * 16);

    f32x4 acc[6] = {};
#define KSTEP(kc, n)                                                     \
    WAITV(n); SB0();                                                     \
    acc[0] = mfma_bf16(hb[kc], ub[0][kc], acc[0]);                       \
    acc[1] = mfma_bf16(hb[kc], ub[1][kc], acc[1]);                       \
    acc[2] = mfma_bf16(hb[kc], ub[2][kc], acc[2]);                       \
    acc[3] = mfma_bf16(hb[kc], ub[3][kc], acc[3]);                       \
    acc[4] = mfma_bf16(hb[kc], ub[4][kc], acc[4]);                       \
    acc[5] = mfma_bf16(hb[kc], ub[5][kc], acc[5]);
    KSTEP(0, 3) KSTEP(1, 2) KSTEP(2, 1) KSTEP(3, 0)
#undef KSTEP

#pragma unroll
    for (int tile = 0; tile < 6; ++tile)
#pragma unroll
      for (int v = 0; v < 4; ++v)
        xacc[q][tile][lk * 4 + v][lr] = acc[tile][v];
    __syncthreads();   // BARRIER B: xacc(s) complete

    if (tid < 256) {
      const int ch = cp >> 3;                 // 16-col tile half
      const int co = (2 * cp) & 15;           // even col offset in tile
      float2 hz = {0.f, 0.f}, hr = {0.f, 0.f}, hn = {0.f, 0.f};
#pragma unroll
      for (int qq = 0; qq < 8; ++qq) {
        float2 a  = *(const float2*)&xacc[qq][ch][crow][co];
        float2 bq = *(const float2*)&xacc[qq][2 + ch][crow][co];
        float2 c  = *(const float2*)&xacc[qq][4 + ch][crow][co];
        hz.x += a.x;  hz.y += a.y;
        hr.x += bq.x; hr.y += bq.y;
        hn.x += c.x;  hn.y += c.y;
      }
      float hnew[2];
#pragma unroll
      for (int j = 0; j < 2; ++j) {
        const float hzj = j ? hz.y : hz.x, hrj = j ? hr.y : hr.x, hnj = j ? hn.y : hn.x;
        const float bz0j = j ? bz0.y : bz0.x, br0j = j ? br0.y : br0.x, bn0j = j ? bn0.y : bn0.x;
        const float bz1j = j ? bz1.y : bz1.x, br1j = j ? br1.y : br1.x, bn1j = j ? bn1.y : bn1.x;
        const float hpj = j ? hp.y : hp.x;
        const float z  = 1.f / (1.f + expf(-(bfsel(xwz, j) + bz0j + hzj + bz1j)));
        const float rr = 1.f / (1.f + expf(-(bfsel(xwr, j) + br0j + hrj + br1j)));
        const float n  = tanhf(bfsel(xwn, j) + bn0j + rr * (hnj + bn1j));
        hnew[j] = z * hpj + (1.f - z) * n;
      }
      hp.x = hnew[0]; hp.y = hnew[1];
      // critical: coalesced publish (lanes 0..15 -> 64B run), own-wave drain
      unsigned pk = bfbits(hnew[0]) | (bfbits(hnew[1]) << 16);
      st_u32_dev(Hw + (par ^ 1) * 8192 + crow * 512 + c0 / 2 + cp, pk);
      WAITV(0);
      // early flag: 4th combiner wave to drain signs the block flag
      if (l == 0) {
        unsigned old = __hip_atomic_fetch_add(&cnt, 1u, __ATOMIC_ACQ_REL,
                                              __HIP_MEMORY_SCOPE_WORKGROUP);
        if (old == 4u * (unsigned)s + 3u)
          st_u32_dev(FLw + r * 16, (unsigned)(s + 1));
      }
      // off-critical-path outputs (plain, coalesced 128B runs)
      *(float2*)&out[((size_t)cb * 256 + t) * 2048 + dir * 1024 + cg] = *(float2*)hnew;
      if (s == 255)
        *(float2*)&out[16777216 + dir * 32768 + (size_t)cb * 1024 + cg] = *(float2*)hnew;
    }
    // no barrier C: xacc(s+1) writes are gated by barrier A(s+1)
  }
}

// ---------------- host ----------------

extern "C" void kernel_launch(void* const* d_in, const int* in_sizes, int n_in,
                              void* d_out, int out_size, void* d_ws, size_t ws_size,
                              hipStream_t stream) {
  const int*   x    = (const int*)d_in[0];
  const float* emb  = (const float*)d_in[1];
  const float* W_f  = (const float*)d_in[2];
  const float* U_f  = (const float*)d_in[3];
  const float* b_f  = (const float*)d_in[4];
  const float* W_b  = (const float*)d_in[5];
  const float* U_b  = (const float*)d_in[6];
  const float* b_b  = (const float*)d_in[7];
  const float* h0_f = (const float*)d_in[8];
  const float* h0_b = (const float*)d_in[9];
  float* out = (float*)d_out;
  char* ws = (char*)d_ws;

  const size_t SZ_A  = (size_t)8192 * 512 * 2;
  const size_t SZ_WT = (size_t)6144 * 512 * 2;
  const size_t SZ_UT = (size_t)6144 * 1024 * 2;
  const size_t SZ_XW = (size_t)8192 * 6144 * 2;
  const size_t SZ_H  = (size_t)4 * 16384 * 4;

  __hip_bfloat16* A   = (__hip_bfloat16*)(ws);
  __hip_bfloat16* WT  = (__hip_bfloat16*)(ws + SZ_A);
  __hip_bfloat16* UT  = (__hip_bfloat16*)(ws + SZ_A + SZ_WT);
  __hip_bfloat16* XW  = (__hip_bfloat16*)(ws + SZ_A + SZ_WT + SZ_UT);
  unsigned*       H   = (unsigned*)(ws + SZ_A + SZ_WT + SZ_UT + SZ_XW);
  unsigned*       FLG = (unsigned*)(ws + SZ_A + SZ_WT + SZ_UT + SZ_XW + SZ_H);

  transpose_cast<<<dim3(96, 16), 256, 0, stream>>>(W_f, WT, 512, 3072);
  transpose_cast<<<dim3(96, 16), 256, 0, stream>>>(W_b, WT + (size_t)3072 * 512, 512, 3072);
  transpose_cast<<<dim3(96, 32), 256, 0, stream>>>(U_f, UT, 1024, 3072);
  transpose_cast<<<dim3(96, 32), 256, 0, stream>>>(U_b, UT + (size_t)3072 * 1024, 1024, 3072);
  gather_embed<<<2048, 256, 0, stream>>>(x, emb, A);
  init_h<<<128, 256, 0, stream>>>(h0_f, h0_b, H, FLG);

  gemm_xw<<<dim3(48, 64), 256, 0, stream>>>(A, WT, XW);

  void* args[] = {(void*)&XW, (void*)&UT, (void*)&b_f, (void*)&b_b,
                  (void*)&h0_f, (void*)&h0_b, (void*)&H, (void*)&FLG, (void*)&out};
  hipLaunchCooperativeKernel((void*)gru_persist, dim3(128), dim3(512),
                             args, 0, stream);
}

// Round 15
// 953.790 us; speedup vs baseline: 1.9778x; 1.0877x over previous
//
#include <hip/hip_runtime.h>
#include <hip/hip_bf16.h>

// Bidirectional GRU encoder, MI355X gfx950.
// Phase 1: prep + one big MFMA GEMM xW = A @ Wcat.
// Phase 2: ONE persistent kernel, grid 128 x 512 (proven co-resident).
//   4 worlds = (dir x batch-half), each 16 rows x 1024 cols on 32 blocks.
//   R9 protocol verbatim (wave0 polls 32 per-block flags; barriers A/B/C;
//   tid0 flag after C). R15 deltas vs R9: (1) coalesced combiner mapping
//   (lanes 0..15 -> consecutive col-pairs), (2) y-out stores after the flag.

typedef __attribute__((ext_vector_type(8))) short bf16x8;     // 8 x bf16
typedef __attribute__((ext_vector_type(4))) float f32x4;      // MFMA acc

__device__ __forceinline__ f32x4 mfma_bf16(bf16x8 a, bf16x8 b, f32x4 c) {
  return __builtin_amdgcn_mfma_f32_16x16x32_bf16(a, b, c, 0, 0, 0);
}

// ---- asm memory helpers ----
__device__ __forceinline__ bf16x8 ld_b128(const __hip_bfloat16* p) {       // plain
  bf16x8 r; asm volatile("global_load_dwordx4 %0, %1, off" : "=v"(r) : "v"(p)); return r;
}
__device__ __forceinline__ bf16x8 ld_b128_dev(const unsigned* p) {         // device-coherent
  bf16x8 r; asm volatile("global_load_dwordx4 %0, %1, off sc0 sc1" : "=v"(r) : "v"(p)); return r;
}
__device__ __forceinline__ unsigned ld_u32_pl(const void* p) {
  unsigned r; asm volatile("global_load_dword %0, %1, off" : "=v"(r) : "v"(p)); return r;
}
__device__ __forceinline__ unsigned ld_u32_dev(const unsigned* p) {
  unsigned r; asm volatile("global_load_dword %0, %1, off sc0 sc1" : "=v"(r) : "v"(p)); return r;
}
__device__ __forceinline__ void st_u32_dev(unsigned* p, unsigned v) {
  asm volatile("global_store_dword %0, %1, off sc0 sc1" :: "v"(p), "v"(v) : "memory");
}

__device__ __forceinline__ float bfsel(unsigned wd, int hi) {
  return __uint_as_float(hi ? (wd & 0xFFFF0000u) : (wd << 16));
}
__device__ __forceinline__ unsigned bfbits(float x) {
  return (unsigned)__builtin_bit_cast(unsigned short, __float2bfloat16(x));
}

#define WAITV(N) asm volatile("s_waitcnt vmcnt(" #N ")" ::: "memory")
#define SB0() __builtin_amdgcn_sched_barrier(0)

// ---------------- prep kernels ----------------

__global__ __launch_bounds__(256) void transpose_cast(const float* __restrict__ src,
                                                      __hip_bfloat16* __restrict__ dst,
                                                      int R, int C) {
  __shared__ float tile[32][33];
  const int tid = threadIdx.x;
  const int bc = blockIdx.x * 32;
  const int br = blockIdx.y * 32;
#pragma unroll
  for (int i = 0; i < 4; ++i) {
    int idx = tid + i * 256;
    int r = idx >> 5, c = idx & 31;
    tile[r][c] = src[(size_t)(br + r) * C + bc + c];
  }
  __syncthreads();
#pragma unroll
  for (int i = 0; i < 4; ++i) {
    int idx = tid + i * 256;
    int r = idx >> 5, c = idx & 31;
    dst[(size_t)(bc + r) * R + br + c] = __float2bfloat16(tile[c][r]);
  }
}

__global__ __launch_bounds__(256) void gather_embed(const int* __restrict__ x,
                                                    const float* __restrict__ emb,
                                                    __hip_bfloat16* __restrict__ A) {
  int ch = blockIdx.x * 256 + threadIdx.x;
  int row = ch >> 6, seg = ch & 63;
  int b = row & 31, t = row >> 5;
  int idx = x[b * 256 + t];
  const float* s = emb + (size_t)idx * 512 + seg * 8;
  float4 f0 = *(const float4*)(s);
  float4 f1 = *(const float4*)(s + 4);
  __hip_bfloat16 h[8];
  h[0] = __float2bfloat16(f0.x); h[1] = __float2bfloat16(f0.y);
  h[2] = __float2bfloat16(f0.z); h[3] = __float2bfloat16(f0.w);
  h[4] = __float2bfloat16(f1.x); h[5] = __float2bfloat16(f1.y);
  h[6] = __float2bfloat16(f1.z); h[7] = __float2bfloat16(f1.w);
  *(uint4*)(A + (size_t)row * 512 + seg * 8) = *(const uint4*)h;
}

// H: [4 worlds][2 par][16 rows][512 u32(bf16-pair)]; FLG: [4][32]*16 stride
__global__ __launch_bounds__(256) void init_h(const float* __restrict__ h0f,
                                              const float* __restrict__ h0b,
                                              unsigned* __restrict__ H,
                                              unsigned* __restrict__ FLG) {
  int i = blockIdx.x * 256 + threadIdx.x;    // [0, 32768)
  int w = i >> 13, rem = i & 8191;
  int row = rem >> 9, p = rem & 511;
  const float* h0 = (w & 1) ? h0b : h0f;
  int b = (w >> 1) * 16 + row;
  float f0 = h0[b * 1024 + 2 * p];
  float f1 = h0[b * 1024 + 2 * p + 1];
  H[w * 16384 + row * 512 + p] = bfbits(f0) | (bfbits(f1) << 16);
  if (i < 2048) FLG[i] = 0u;
}

// ---------------- big GEMM: xW[8192][6144] = A[8192][512] @ WT[6144][512]^T ----------------
__global__ __launch_bounds__(256) void gemm_xw(const __hip_bfloat16* __restrict__ A,
                                               const __hip_bfloat16* __restrict__ B,
                                               __hip_bfloat16* __restrict__ C) {
  __shared__ char sm[2 * 128 * 80];
  const int tid = threadIdx.x;
  const int bn = blockIdx.x, bm = blockIdx.y;
  const int l = tid & 63, w = tid >> 6;
  const int wm = w & 1, wn = w >> 1;
  const int lr = l & 15, lk = l >> 4;
  f32x4 acc[4][4] = {};
  for (int k0 = 0; k0 < 512; k0 += 32) {
    __syncthreads();
#pragma unroll
    for (int i = 0; i < 2; ++i) {
      int ch = tid + i * 256;
      int row = ch >> 2, kq = ch & 3;
      uint4 va = *(const uint4*)(A + (size_t)(bm * 128 + row) * 512 + k0 + kq * 8);
      *(uint4*)(sm + row * 80 + kq * 16) = va;
      uint4 vb = *(const uint4*)(B + (size_t)(bn * 128 + row) * 512 + k0 + kq * 8);
      *(uint4*)(sm + 10240 + row * 80 + kq * 16) = vb;
    }
    __syncthreads();
    bf16x8 af[4], bfr[4];
#pragma unroll
    for (int m = 0; m < 4; ++m)
      af[m] = *(const bf16x8*)(sm + (wm * 64 + m * 16 + lr) * 80 + lk * 16);
#pragma unroll
    for (int n = 0; n < 4; ++n)
      bfr[n] = *(const bf16x8*)(sm + 10240 + (wn * 64 + n * 16 + lr) * 80 + lk * 16);
#pragma unroll
    for (int m = 0; m < 4; ++m)
#pragma unroll
      for (int n = 0; n < 4; ++n)
        acc[m][n] = mfma_bf16(af[m], bfr[n], acc[m][n]);
  }
#pragma unroll
  for (int m = 0; m < 4; ++m)
#pragma unroll
    for (int n = 0; n < 4; ++n)
#pragma unroll
      for (int v = 0; v < 4; ++v) {
        int row = bm * 128 + wm * 64 + m * 16 + lk * 4 + v;
        int col = bn * 128 + wn * 64 + n * 16 + lr;
        C[(size_t)row * 6144 + col] = __float2bfloat16(acc[m][n][v]);
      }
}

// ---------------- persistent GRU: 4 worlds x 32 blocks (R9 + coalescing) ----------------
// grid 128: world w = bi&3 (dir=w&1, batch-half mh=w>>1), rank r = bi>>2.
// Block owns cols r*32..+32. 8 waves = K-split 8 (128 K each), ub pinned.
// Step: [xw issue(q<4)] [wave0 poll 32 flags>=s] [WAITV(0)] [barrier A]
//       [hb dev loads + MFMA ladder] [xacc] [barrier B]
//       [tid<256: combine + coalesced publish + WAITV(0)] [barrier C]
//       [tid0 flag(s+1)] [tid<256: y-out stores (off critical path)]
__global__ __launch_bounds__(512, 2) void gru_persist(
    const __hip_bfloat16* __restrict__ xW,
    const __hip_bfloat16* __restrict__ UT,
    const float* __restrict__ bias_f,
    const float* __restrict__ bias_b,
    const float* __restrict__ h0_f,
    const float* __restrict__ h0_b,
    unsigned* H,                // [4][2][16][512] u32
    unsigned* FLG,              // [4][32] stride-16 u32
    float* __restrict__ out) {
  const int bi = blockIdx.x;
  const int w = bi & 3;
  const int r = bi >> 2;
  const int dir = w & 1, mh = w >> 1;
  const int tid = threadIdx.x;
  const int l = tid & 63, q = tid >> 6;
  const int lr = l & 15, lk = l >> 4;
  const int c0 = r * 32;

  __shared__ float xacc[8][6][16][20];   // [q][tile][row][col+pad]

  // ---- pin U: 6 tiles (g,ch), K-slice q*128 ----
  bf16x8 ub[6][4];
#pragma unroll
  for (int g = 0; g < 3; ++g)
#pragma unroll
    for (int ch = 0; ch < 2; ++ch) {
      const __hip_bfloat16* Urow =
          UT + (size_t)(dir * 3072 + g * 1024 + c0 + ch * 16 + lr) * 1024 + q * 128 + lk * 8;
#pragma unroll
      for (int kc = 0; kc < 4; ++kc)
        ub[g * 2 + ch][kc] = ld_b128(Urow + kc * 32);
    }
  WAITV(0);
  SB0();

  // ---- combiner-thread invariants (tid<256): COALESCED mapping ----
  // crow = tid>>4 (row), cp = tid&15 (col-pair): lanes 0..15 -> consecutive cols.
  const int crow = (tid >> 4) & 15;     // batch row within world
  const int cp = tid & 15;              // local col-pair 0..15
  const int cb = mh * 16 + crow;        // global batch row
  const int cg = c0 + 2 * cp;           // global h col (even)
  float2 bz0, br0, bn0, bz1, br1, bn1, hp;
  if (tid < 256) {
    const float* bias = dir ? bias_b : bias_f;
    bz0 = *(const float2*)&bias[cg];
    br0 = *(const float2*)&bias[1024 + cg];
    bn0 = *(const float2*)&bias[2048 + cg];
    bz1 = *(const float2*)&bias[3072 + cg];
    br1 = *(const float2*)&bias[4096 + cg];
    bn1 = *(const float2*)&bias[5120 + cg];
    const float* h0 = dir ? h0_b : h0_f;
    hp = *(const float2*)&h0[(size_t)cb * 1024 + cg];
  }

  unsigned* Hw  = H + w * 16384;
  unsigned* FLw = FLG + w * 512;
  const unsigned* flp = FLw + (l & 31) * 16;   // wave0's poll targets

  for (int s = 0; s < 256; ++s) {
    const int par = s & 1;
    const int t = dir ? (255 - s) : s;

    // ---- xW loads (combiner threads; now coalesced 64B runs per 16 lanes) ----
    unsigned xwz = 0, xwr = 0, xwn = 0;
    if (q < 4) {
      const __hip_bfloat16* xp = xW + (size_t)(t * 32 + cb) * 6144 + dir * 3072 + cg;
      xwz = ld_u32_pl(xp);
      xwr = ld_u32_pl(xp + 1024);
      xwn = ld_u32_pl(xp + 2048);
    }

    // ---- wave0 polls world's 32 flags >= s (h(s) fully published) ----
    if (q == 0) {
      const unsigned tg = (unsigned)s;
      for (;;) {
        unsigned f = ld_u32_dev(flp);
        WAITV(0);
        SB0();
        if (__all(f >= tg)) break;
      }
    }
    WAITV(0);          // non-pollers: drain xw so everyone has 0 outstanding
    __syncthreads();   // BARRIER A: h(s) readable

    // ---- h loads (device-coherent) + MFMA ladder ----
    const unsigned* hrow = Hw + par * 8192 + lr * 512 + q * 64 + lk * 4;
    bf16x8 hb[4];
#pragma unroll
    for (int kc = 0; kc < 4; ++kc)
      hb[kc] = ld_b128_dev(hrow + kc * 16);

    f32x4 acc[6] = {};
#define KSTEP(kc, n)                                                     \
    WAITV(n); SB0();                                                     \
    acc[0] = mfma_bf16(hb[kc], ub[0][kc], acc[0]);                       \
    acc[1] = mfma_bf16(hb[kc], ub[1][kc], acc[1]);                       \
    acc[2] = mfma_bf16(hb[kc], ub[2][kc], acc[2]);                       \
    acc[3] = mfma_bf16(hb[kc], ub[3][kc], acc[3]);                       \
    acc[4] = mfma_bf16(hb[kc], ub[4][kc], acc[4]);                       \
    acc[5] = mfma_bf16(hb[kc], ub[5][kc], acc[5]);
    KSTEP(0, 3) KSTEP(1, 2) KSTEP(2, 1) KSTEP(3, 0)
#undef KSTEP

#pragma unroll
    for (int tile = 0; tile < 6; ++tile)
#pragma unroll
      for (int v = 0; v < 4; ++v)
        xacc[q][tile][lk * 4 + v][lr] = acc[tile][v];
    __syncthreads();   // BARRIER B: partials complete

    float hnew[2];
    if (tid < 256) {
      const int ch = cp >> 3;                 // 16-col tile half
      const int co = (2 * cp) & 15;           // even col offset in tile
      float2 hz = {0.f, 0.f}, hr = {0.f, 0.f}, hn = {0.f, 0.f};
#pragma unroll
      for (int qq = 0; qq < 8; ++qq) {
        float2 a  = *(const float2*)&xacc[qq][ch][crow][co];
        float2 bq = *(const float2*)&xacc[qq][2 + ch][crow][co];
        float2 c  = *(const float2*)&xacc[qq][4 + ch][crow][co];
        hz.x += a.x;  hz.y += a.y;
        hr.x += bq.x; hr.y += bq.y;
        hn.x += c.x;  hn.y += c.y;
      }
#pragma unroll
      for (int j = 0; j < 2; ++j) {
        const float hzj = j ? hz.y : hz.x, hrj = j ? hr.y : hr.x, hnj = j ? hn.y : hn.x;
        const float bz0j = j ? bz0.y : bz0.x, br0j = j ? br0.y : br0.x, bn0j = j ? bn0.y : bn0.x;
        const float bz1j = j ? bz1.y : bz1.x, br1j = j ? br1.y : br1.x, bn1j = j ? bn1.y : bn1.x;
        const float hpj = j ? hp.y : hp.x;
        const float z  = 1.f / (1.f + expf(-(bfsel(xwz, j) + bz0j + hzj + bz1j)));
        const float rr = 1.f / (1.f + expf(-(bfsel(xwr, j) + br0j + hrj + br1j)));
        const float n  = tanhf(bfsel(xwn, j) + bn0j + rr * (hnj + bn1j));
        hnew[j] = z * hpj + (1.f - z) * n;
      }
      hp.x = hnew[0]; hp.y = hnew[1];
      // critical publish: one 4B device store, COALESCED (16 lanes = 64B run)
      unsigned pk = bfbits(hnew[0]) | (bfbits(hnew[1]) << 16);
      st_u32_dev(Hw + (par ^ 1) * 8192 + crow * 512 + c0 / 2 + cp, pk);
      WAITV(0);        // drain publish only (y-outs not yet issued)
    }
    __syncthreads();   // BARRIER C: all publishes at coherence point
    if (tid == 0) st_u32_dev(FLw + r * 16, (unsigned)(s + 1));
    // y-out stores AFTER the flag: off the inter-block critical path
    if (tid < 256) {
      *(float2*)&out[((size_t)cb * 256 + t) * 2048 + dir * 1024 + cg] = *(float2*)hnew;
      if (s == 255)
        *(float2*)&out[16777216 + dir * 32768 + (size_t)cb * 1024 + cg] = *(float2*)hnew;
    }
  }
}

// ---------------- host ----------------

extern "C" void kernel_launch(void* const* d_in, const int* in_sizes, int n_in,
                              void* d_out, int out_size, void* d_ws, size_t ws_size,
                              hipStream_t stream) {
  const int*   x    = (const int*)d_in[0];
  const float* emb  = (const float*)d_in[1];
  const float* W_f  = (const float*)d_in[2];
  const float* U_f  = (const float*)d_in[3];
  const float* b_f  = (const float*)d_in[4];
  const float* W_b  = (const float*)d_in[5];
  const float* U_b  = (const float*)d_in[6];
  const float* b_b  = (const float*)d_in[7];
  const float* h0_f = (const float*)d_in[8];
  const float* h0_b = (const float*)d_in[9];
  float* out = (float*)d_out;
  char* ws = (char*)d_ws;

  const size_t SZ_A  = (size_t)8192 * 512 * 2;
  const size_t SZ_WT = (size_t)6144 * 512 * 2;
  const size_t SZ_UT = (size_t)6144 * 1024 * 2;
  const size_t SZ_XW = (size_t)8192 * 6144 * 2;
  const size_t SZ_H  = (size_t)4 * 16384 * 4;

  __hip_bfloat16* A   = (__hip_bfloat16*)(ws);
  __hip_bfloat16* WT  = (__hip_bfloat16*)(ws + SZ_A);
  __hip_bfloat16* UT  = (__hip_bfloat16*)(ws + SZ_A + SZ_WT);
  __hip_bfloat16* XW  = (__hip_bfloat16*)(ws + SZ_A + SZ_WT + SZ_UT);
  unsigned*       H   = (unsigned*)(ws + SZ_A + SZ_WT + SZ_UT + SZ_XW);
  unsigned*       FLG = (unsigned*)(ws + SZ_A + SZ_WT + SZ_UT + SZ_XW + SZ_H);

  transpose_cast<<<dim3(96, 16), 256, 0, stream>>>(W_f, WT, 512, 3072);
  transpose_cast<<<dim3(96, 16), 256, 0, stream>>>(W_b, WT + (size_t)3072 * 512, 512, 3072);
  transpose_cast<<<dim3(96, 32), 256, 0, stream>>>(U_f, UT, 1024, 3072);
  transpose_cast<<<dim3(96, 32), 256, 0, stream>>>(U_b, UT + (size_t)3072 * 1024, 1024, 3072);
  gather_embed<<<2048, 256, 0, stream>>>(x, emb, A);
  init_h<<<128, 256, 0, stream>>>(h0_f, h0_b, H, FLG);

  gemm_xw<<<dim3(48, 64), 256, 0, stream>>>(A, WT, XW);

  void* args[] = {(void*)&XW, (void*)&UT, (void*)&b_f, (void*)&b_b,
                  (void*)&h0_f, (void*)&h0_b, (void*)&H, (void*)&FLG, (void*)&out};
  hipLaunchCooperativeKernel((void*)gru_persist, dim3(128), dim3(512),
                             args, 0, stream);
}

// Round 16
// 953.459 us; speedup vs baseline: 1.9785x; 1.0003x over previous
//
#include <hip/hip_runtime.h>
#include <hip/hip_bf16.h>

// Bidirectional GRU encoder, MI355X gfx950.
// Phase 1: prep + one big MFMA GEMM xW = A @ Wcat (global_load_lds staging).
// Phase 2: ONE persistent kernel (R15 champion, byte-identical):
//   4 worlds = (dir x batch-half) x 32 blocks; wave0 polls 32 flags;
//   barriers A/B/C; coalesced combiner mapping; y-outs after the flag.

typedef __attribute__((ext_vector_type(8))) short bf16x8;     // 8 x bf16
typedef __attribute__((ext_vector_type(4))) float f32x4;      // MFMA acc

__device__ __forceinline__ f32x4 mfma_bf16(bf16x8 a, bf16x8 b, f32x4 c) {
  return __builtin_amdgcn_mfma_f32_16x16x32_bf16(a, b, c, 0, 0, 0);
}

// ---- asm memory helpers ----
__device__ __forceinline__ bf16x8 ld_b128(const __hip_bfloat16* p) {       // plain
  bf16x8 r; asm volatile("global_load_dwordx4 %0, %1, off" : "=v"(r) : "v"(p)); return r;
}
__device__ __forceinline__ bf16x8 ld_b128_dev(const unsigned* p) {         // device-coherent
  bf16x8 r; asm volatile("global_load_dwordx4 %0, %1, off sc0 sc1" : "=v"(r) : "v"(p)); return r;
}
__device__ __forceinline__ unsigned ld_u32_pl(const void* p) {
  unsigned r; asm volatile("global_load_dword %0, %1, off" : "=v"(r) : "v"(p)); return r;
}
__device__ __forceinline__ unsigned ld_u32_dev(const unsigned* p) {
  unsigned r; asm volatile("global_load_dword %0, %1, off sc0 sc1" : "=v"(r) : "v"(p)); return r;
}
__device__ __forceinline__ void st_u32_dev(unsigned* p, unsigned v) {
  asm volatile("global_store_dword %0, %1, off sc0 sc1" :: "v"(p), "v"(v) : "memory");
}

__device__ __forceinline__ float bfsel(unsigned wd, int hi) {
  return __uint_as_float(hi ? (wd & 0xFFFF0000u) : (wd << 16));
}
__device__ __forceinline__ unsigned bfbits(float x) {
  return (unsigned)__builtin_bit_cast(unsigned short, __float2bfloat16(x));
}

#define WAITV(N) asm volatile("s_waitcnt vmcnt(" #N ")" ::: "memory")
#define SB0() __builtin_amdgcn_sched_barrier(0)

typedef __attribute__((address_space(1))) const unsigned GUint;
typedef __attribute__((address_space(3))) unsigned LUint;
__device__ __forceinline__ void gld_lds16(const __hip_bfloat16* g, __hip_bfloat16* l) {
  __builtin_amdgcn_global_load_lds((GUint*)g, (LUint*)l, 16, 0, 0);
}

// ---------------- prep kernels ----------------

__global__ __launch_bounds__(256) void transpose_cast(const float* __restrict__ src,
                                                      __hip_bfloat16* __restrict__ dst,
                                                      int R, int C) {
  __shared__ float tile[32][33];
  const int tid = threadIdx.x;
  const int bc = blockIdx.x * 32;
  const int br = blockIdx.y * 32;
#pragma unroll
  for (int i = 0; i < 4; ++i) {
    int idx = tid + i * 256;
    int r = idx >> 5, c = idx & 31;
    tile[r][c] = src[(size_t)(br + r) * C + bc + c];
  }
  __syncthreads();
#pragma unroll
  for (int i = 0; i < 4; ++i) {
    int idx = tid + i * 256;
    int r = idx >> 5, c = idx & 31;
    dst[(size_t)(bc + r) * R + br + c] = __float2bfloat16(tile[c][r]);
  }
}

__global__ __launch_bounds__(256) void gather_embed(const int* __restrict__ x,
                                                    const float* __restrict__ emb,
                                                    __hip_bfloat16* __restrict__ A) {
  int ch = blockIdx.x * 256 + threadIdx.x;
  int row = ch >> 6, seg = ch & 63;
  int b = row & 31, t = row >> 5;
  int idx = x[b * 256 + t];
  const float* s = emb + (size_t)idx * 512 + seg * 8;
  float4 f0 = *(const float4*)(s);
  float4 f1 = *(const float4*)(s + 4);
  __hip_bfloat16 h[8];
  h[0] = __float2bfloat16(f0.x); h[1] = __float2bfloat16(f0.y);
  h[2] = __float2bfloat16(f0.z); h[3] = __float2bfloat16(f0.w);
  h[4] = __float2bfloat16(f1.x); h[5] = __float2bfloat16(f1.y);
  h[6] = __float2bfloat16(f1.z); h[7] = __float2bfloat16(f1.w);
  *(uint4*)(A + (size_t)row * 512 + seg * 8) = *(const uint4*)h;
}

// H: [4 worlds][2 par][16 rows][512 u32(bf16-pair)]; FLG: [4][32]*16 stride
__global__ __launch_bounds__(256) void init_h(const float* __restrict__ h0f,
                                              const float* __restrict__ h0b,
                                              unsigned* __restrict__ H,
                                              unsigned* __restrict__ FLG) {
  int i = blockIdx.x * 256 + threadIdx.x;    // [0, 32768)
  int w = i >> 13, rem = i & 8191;
  int row = rem >> 9, p = rem & 511;
  const float* h0 = (w & 1) ? h0b : h0f;
  int b = (w >> 1) * 16 + row;
  float f0 = h0[b * 1024 + 2 * p];
  float f1 = h0[b * 1024 + 2 * p + 1];
  H[w * 16384 + row * 512 + p] = bfbits(f0) | (bfbits(f1) << 16);
  if (i < 2048) FLG[i] = 0u;
}

// ---------------- big GEMM: xW[8192][6144] = A[8192][512] @ WT[6144][512]^T ----------------
// m97-style: global_load_lds width-16 staging into linear [128][32] LDS tiles.
__global__ __launch_bounds__(256) void gemm_xw(const __hip_bfloat16* __restrict__ A,
                                               const __hip_bfloat16* __restrict__ B,
                                               __hip_bfloat16* __restrict__ C) {
  __shared__ __hip_bfloat16 smA[128 * 32];   // 8 KB, linear row-major [row][k]
  __shared__ __hip_bfloat16 smB[128 * 32];   // 8 KB
  const int tid = threadIdx.x;
  const int bn = blockIdx.x, bm = blockIdx.y;
  const int l = tid & 63, w = tid >> 6;
  const int wm = w & 1, wn = w >> 1;
  const int lr = l & 15, lk = l >> 4;
  f32x4 acc[4][4] = {};
  for (int k0 = 0; k0 < 512; k0 += 32) {
    __syncthreads();
    // stage A,B tiles: 8 wave-instructions each (chunk j covers rows j*16..+16)
#pragma unroll
    for (int i = 0; i < 2; ++i) {
      const int j = w + i * 4;          // 0..7
      const int c = j * 64 + l;         // 16B-chunk index 0..511
      const int row = c >> 2, kq = c & 3;
      gld_lds16(A + (size_t)(bm * 128 + row) * 512 + k0 + kq * 8, smA + j * 512);
      gld_lds16(B + (size_t)(bn * 128 + row) * 512 + k0 + kq * 8, smB + j * 512);
    }
    WAITV(0);
    __syncthreads();
    bf16x8 af[4], bfr[4];
#pragma unroll
    for (int m = 0; m < 4; ++m)
      af[m] = *(const bf16x8*)(smA + (wm * 64 + m * 16 + lr) * 32 + lk * 8);
#pragma unroll
    for (int n = 0; n < 4; ++n)
      bfr[n] = *(const bf16x8*)(smB + (wn * 64 + n * 16 + lr) * 32 + lk * 8);
#pragma unroll
    for (int m = 0; m < 4; ++m)
#pragma unroll
      for (int n = 0; n < 4; ++n)
        acc[m][n] = mfma_bf16(af[m], bfr[n], acc[m][n]);
  }
#pragma unroll
  for (int m = 0; m < 4; ++m)
#pragma unroll
    for (int n = 0; n < 4; ++n)
#pragma unroll
      for (int v = 0; v < 4; ++v) {
        int row = bm * 128 + wm * 64 + m * 16 + lk * 4 + v;
        int col = bn * 128 + wn * 64 + n * 16 + lr;
        C[(size_t)row * 6144 + col] = __float2bfloat16(acc[m][n][v]);
      }
}

// ---------------- persistent GRU: 4 worlds x 32 blocks (R15 champion, unchanged) ----------------
__global__ __launch_bounds__(512, 2) void gru_persist(
    const __hip_bfloat16* __restrict__ xW,
    const __hip_bfloat16* __restrict__ UT,
    const float* __restrict__ bias_f,
    const float* __restrict__ bias_b,
    const float* __restrict__ h0_f,
    const float* __restrict__ h0_b,
    unsigned* H,                // [4][2][16][512] u32
    unsigned* FLG,              // [4][32] stride-16 u32
    float* __restrict__ out) {
  const int bi = blockIdx.x;
  const int w = bi & 3;
  const int r = bi >> 2;
  const int dir = w & 1, mh = w >> 1;
  const int tid = threadIdx.x;
  const int l = tid & 63, q = tid >> 6;
  const int lr = l & 15, lk = l >> 4;
  const int c0 = r * 32;

  __shared__ float xacc[8][6][16][20];   // [q][tile][row][col+pad]

  // ---- pin U: 6 tiles (g,ch), K-slice q*128 ----
  bf16x8 ub[6][4];
#pragma unroll
  for (int g = 0; g < 3; ++g)
#pragma unroll
    for (int ch = 0; ch < 2; ++ch) {
      const __hip_bfloat16* Urow =
          UT + (size_t)(dir * 3072 + g * 1024 + c0 + ch * 16 + lr) * 1024 + q * 128 + lk * 8;
#pragma unroll
      for (int kc = 0; kc < 4; ++kc)
        ub[g * 2 + ch][kc] = ld_b128(Urow + kc * 32);
    }
  WAITV(0);
  SB0();

  // ---- combiner-thread invariants (tid<256): COALESCED mapping ----
  const int crow = (tid >> 4) & 15;     // batch row within world
  const int cp = tid & 15;              // local col-pair 0..15
  const int cb = mh * 16 + crow;        // global batch row
  const int cg = c0 + 2 * cp;           // global h col (even)
  float2 bz0, br0, bn0, bz1, br1, bn1, hp;
  if (tid < 256) {
    const float* bias = dir ? bias_b : bias_f;
    bz0 = *(const float2*)&bias[cg];
    br0 = *(const float2*)&bias[1024 + cg];
    bn0 = *(const float2*)&bias[2048 + cg];
    bz1 = *(const float2*)&bias[3072 + cg];
    br1 = *(const float2*)&bias[4096 + cg];
    bn1 = *(const float2*)&bias[5120 + cg];
    const float* h0 = dir ? h0_b : h0_f;
    hp = *(const float2*)&h0[(size_t)cb * 1024 + cg];
  }

  unsigned* Hw  = H + w * 16384;
  unsigned* FLw = FLG + w * 512;
  const unsigned* flp = FLw + (l & 31) * 16;   // wave0's poll targets

  for (int s = 0; s < 256; ++s) {
    const int par = s & 1;
    const int t = dir ? (255 - s) : s;

    // ---- xW loads (combiner threads; coalesced 64B runs per 16 lanes) ----
    unsigned xwz = 0, xwr = 0, xwn = 0;
    if (q < 4) {
      const __hip_bfloat16* xp = xW + (size_t)(t * 32 + cb) * 6144 + dir * 3072 + cg;
      xwz = ld_u32_pl(xp);
      xwr = ld_u32_pl(xp + 1024);
      xwn = ld_u32_pl(xp + 2048);
    }

    // ---- wave0 polls world's 32 flags >= s (h(s) fully published) ----
    if (q == 0) {
      const unsigned tg = (unsigned)s;
      for (;;) {
        unsigned f = ld_u32_dev(flp);
        WAITV(0);
        SB0();
        if (__all(f >= tg)) break;
      }
    }
    WAITV(0);          // non-pollers: drain xw so everyone has 0 outstanding
    __syncthreads();   // BARRIER A: h(s) readable

    // ---- h loads (device-coherent) + MFMA ladder ----
    const unsigned* hrow = Hw + par * 8192 + lr * 512 + q * 64 + lk * 4;
    bf16x8 hb[4];
#pragma unroll
    for (int kc = 0; kc < 4; ++kc)
      hb[kc] = ld_b128_dev(hrow + kc * 16);

    f32x4 acc[6] = {};
#define KSTEP(kc, n)                                                     \
    WAITV(n); SB0();                                                     \
    acc[0] = mfma_bf16(hb[kc], ub[0][kc], acc[0]);                       \
    acc[1] = mfma_bf16(hb[kc], ub[1][kc], acc[1]);                       \
    acc[2] = mfma_bf16(hb[kc], ub[2][kc], acc[2]);                       \
    acc[3] = mfma_bf16(hb[kc], ub[3][kc], acc[3]);                       \
    acc[4] = mfma_bf16(hb[kc], ub[4][kc], acc[4]);                       \
    acc[5] = mfma_bf16(hb[kc], ub[5][kc], acc[5]);
    KSTEP(0, 3) KSTEP(1, 2) KSTEP(2, 1) KSTEP(3, 0)
#undef KSTEP

#pragma unroll
    for (int tile = 0; tile < 6; ++tile)
#pragma unroll
      for (int v = 0; v < 4; ++v)
        xacc[q][tile][lk * 4 + v][lr] = acc[tile][v];
    __syncthreads();   // BARRIER B: partials complete

    float hnew[2];
    if (tid < 256) {
      const int ch = cp >> 3;                 // 16-col tile half
      const int co = (2 * cp) & 15;           // even col offset in tile
      float2 hz = {0.f, 0.f}, hr = {0.f, 0.f}, hn = {0.f, 0.f};
#pragma unroll
      for (int qq = 0; qq < 8; ++qq) {
        float2 a  = *(const float2*)&xacc[qq][ch][crow][co];
        float2 bq = *(const float2*)&xacc[qq][2 + ch][crow][co];
        float2 c  = *(const float2*)&xacc[qq][4 + ch][crow][co];
        hz.x += a.x;  hz.y += a.y;
        hr.x += bq.x; hr.y += bq.y;
        hn.x += c.x;  hn.y += c.y;
      }
#pragma unroll
      for (int j = 0; j < 2; ++j) {
        const float hzj = j ? hz.y : hz.x, hrj = j ? hr.y : hr.x, hnj = j ? hn.y : hn.x;
        const float bz0j = j ? bz0.y : bz0.x, br0j = j ? br0.y : br0.x, bn0j = j ? bn0.y : bn0.x;
        const float bz1j = j ? bz1.y : bz1.x, br1j = j ? br1.y : br1.x, bn1j = j ? bn1.y : bn1.x;
        const float hpj = j ? hp.y : hp.x;
        const float z  = 1.f / (1.f + expf(-(bfsel(xwz, j) + bz0j + hzj + bz1j)));
        const float rr = 1.f / (1.f + expf(-(bfsel(xwr, j) + br0j + hrj + br1j)));
        const float n  = tanhf(bfsel(xwn, j) + bn0j + rr * (hnj + bn1j));
        hnew[j] = z * hpj + (1.f - z) * n;
      }
      hp.x = hnew[0]; hp.y = hnew[1];
      // critical publish: one 4B device store, COALESCED (16 lanes = 64B run)
      unsigned pk = bfbits(hnew[0]) | (bfbits(hnew[1]) << 16);
      st_u32_dev(Hw + (par ^ 1) * 8192 + crow * 512 + c0 / 2 + cp, pk);
      WAITV(0);        // drain publish only (y-outs not yet issued)
    }
    __syncthreads();   // BARRIER C: all publishes at coherence point
    if (tid == 0) st_u32_dev(FLw + r * 16, (unsigned)(s + 1));
    // y-out stores AFTER the flag: off the inter-block critical path
    if (tid < 256) {
      *(float2*)&out[((size_t)cb * 256 + t) * 2048 + dir * 1024 + cg] = *(float2*)hnew;
      if (s == 255)
        *(float2*)&out[16777216 + dir * 32768 + (size_t)cb * 1024 + cg] = *(float2*)hnew;
    }
  }
}

// ---------------- host ----------------

extern "C" void kernel_launch(void* const* d_in, const int* in_sizes, int n_in,
                              void* d_out, int out_size, void* d_ws, size_t ws_size,
                              hipStream_t stream) {
  const int*   x    = (const int*)d_in[0];
  const float* emb  = (const float*)d_in[1];
  const float* W_f  = (const float*)d_in[2];
  const float* U_f  = (const float*)d_in[3];
  const float* b_f  = (const float*)d_in[4];
  const float* W_b  = (const float*)d_in[5];
  const float* U_b  = (const float*)d_in[6];
  const float* b_b  = (const float*)d_in[7];
  const float* h0_f = (const float*)d_in[8];
  const float* h0_b = (const float*)d_in[9];
  float* out = (float*)d_out;
  char* ws = (char*)d_ws;

  const size_t SZ_A  = (size_t)8192 * 512 * 2;
  const size_t SZ_WT = (size_t)6144 * 512 * 2;
  const size_t SZ_UT = (size_t)6144 * 1024 * 2;
  const size_t SZ_XW = (size_t)8192 * 6144 * 2;
  const size_t SZ_H  = (size_t)4 * 16384 * 4;

  __hip_bfloat16* A   = (__hip_bfloat16*)(ws);
  __hip_bfloat16* WT  = (__hip_bfloat16*)(ws + SZ_A);
  __hip_bfloat16* UT  = (__hip_bfloat16*)(ws + SZ_A + SZ_WT);
  __hip_bfloat16* XW  = (__hip_bfloat16*)(ws + SZ_A + SZ_WT + SZ_UT);
  unsigned*       H   = (unsigned*)(ws + SZ_A + SZ_WT + SZ_UT + SZ_XW);
  unsigned*       FLG = (unsigned*)(ws + SZ_A + SZ_WT + SZ_UT + SZ_XW + SZ_H);

  transpose_cast<<<dim3(96, 16), 256, 0, stream>>>(W_f, WT, 512, 3072);
  transpose_cast<<<dim3(96, 16), 256, 0, stream>>>(W_b, WT + (size_t)3072 * 512, 512, 3072);
  transpose_cast<<<dim3(96, 32), 256, 0, stream>>>(U_f, UT, 1024, 3072);
  transpose_cast<<<dim3(96, 32), 256, 0, stream>>>(U_b, UT + (size_t)3072 * 1024, 1024, 3072);
  gather_embed<<<2048, 256, 0, stream>>>(x, emb, A);
  init_h<<<128, 256, 0, stream>>>(h0_f, h0_b, H, FLG);

  gemm_xw<<<dim3(48, 64), 256, 0, stream>>>(A, WT, XW);

  void* args[] = {(void*)&XW, (void*)&UT, (void*)&b_f, (void*)&b_b,
                  (void*)&h0_f, (void*)&h0_b, (void*)&H, (void*)&FLG, (void*)&out};
  hipLaunchCooperativeKernel((void*)gru_persist, dim3(128), dim3(512),
                             args, 0, stream);
}